// Round 12
// baseline (117.017 us; speedup 1.0000x reference)
//
#include <hip/hip_runtime.h>

// ---------------------------------------------------------------------------
// AMM chain, round 12: Q-fold dropped (28 GF vs 40.7 GF total) — direct
// two-GEMM ISTA on the proven gt32 kernel. All GEMMs NT fp16 MFMA f32-accum,
// 32x64 tiles, 4 waves (2N x 2K), 4-buf ahead-2 gload_lds, vmcnt(6/3/0).
//   D1 conv | D2 C1[q|be2] | D3 {betas, ypart} | D4 yb | D5 z0(soft) |
//   D6..12 alternating {c = z@Ve (N=1024,K=2048)}, {z = soft(z0+z-c@Ve^T)} |
//   D13 out = ypart + soft(z0 + z - c@Ve^T)
// Graph == R2's verified chain (absmax 0.0156 there).
// ---------------------------------------------------------------------------

typedef _Float16 f16x8 __attribute__((ext_vector_type(8)));
typedef _Float16 f16x4 __attribute__((ext_vector_type(4)));
typedef float f32x4 __attribute__((ext_vector_type(4)));

enum { EPI_SPLIT, EPI_BH, EPI_YP, EPI_SOFT, EPI_ZUP, EPI_ZUPF };

typedef const __attribute__((address_space(1))) void* gas_ptr;
typedef __attribute__((address_space(3))) void* las_ptr;

__device__ __forceinline__ void gload16(const void* g, void* l) {
  __builtin_amdgcn_global_load_lds((gas_ptr)g, (las_ptr)l, 16, 0, 0);
}

__device__ __forceinline__ float softt(float t) {
  float s = fabsf(t) - 1.0f;
  s = s > 0.0f ? s : 0.0f;
  return copysignf(s, t);
}

// ---------------------------------------------------------------------------
// conversions. block (32,8).
// z=0..3 transposing f32->f16: [ke, k1*s1(col), v0, ve] -> [Bcat, Bcat+2M,
// vt0T, veT].  z=4 plain f32->f16 x4: x, ve, vt1, k0*s0(row).
// ---------------------------------------------------------------------------
__global__ __launch_bounds__(256) void convAll(
    const float* __restrict__ ke, const float* __restrict__ k1,
    const float* __restrict__ v0, const float* __restrict__ ve,
    _Float16* __restrict__ oKe, _Float16* __restrict__ oK1,
    _Float16* __restrict__ oV0, _Float16* __restrict__ oVeT,
    const float* __restrict__ s1, const float* __restrict__ s0,
    const float4* __restrict__ px, f16x4* __restrict__ qx,
    const float4* __restrict__ pve, f16x4* __restrict__ qve,
    const float4* __restrict__ pv1, f16x4* __restrict__ qv1,
    const float4* __restrict__ pk0, f16x4* __restrict__ qk0) {
  const int z = blockIdx.z;
  if (z == 4) {
    const int n_x = 262144, n_ve = 524288, n_v1 = 524288, n_k0 = 262144;
    const int total = n_x + n_ve + n_v1 + n_k0;
    const int bid = blockIdx.y * 32 + blockIdx.x;
    for (int i = bid * 256 + threadIdx.y * 32 + threadIdx.x; i < total;
         i += 2048 * 256) {
      int j = i;
      const float4* s;
      f16x4* d;
      float sc = 1.0f;
      if (j < n_x) {
        s = px; d = qx;
      } else if ((j -= n_x) < n_ve) {
        s = pve; d = qve;
      } else if ((j -= n_ve) < n_v1) {
        s = pv1; d = qv1;
      } else {
        j -= n_v1; s = pk0; d = qk0; sc = s0[j >> 8];
      }
      float4 v = s[j];
      f16x4 h = {(_Float16)(v.x * sc), (_Float16)(v.y * sc),
                 (_Float16)(v.z * sc), (_Float16)(v.w * sc)};
      d[j] = h;
    }
    return;
  }
  const float* in = z == 0 ? ke : z == 1 ? k1 : z == 2 ? v0 : ve;
  _Float16* out = z == 0 ? oKe : z == 1 ? oK1 : z == 2 ? oV0 : oVeT;
  const int R = (z == 2) ? 1024 : 2048;
  const int mode = (z == 1) ? 1 : 0;
  __shared__ float t[32][33];
  const int tx = threadIdx.x, ty = threadIdx.y;
  const int c0 = blockIdx.x * 32, r0 = blockIdx.y * 32;
  if (r0 >= R) return;  // uniform per block
#pragma unroll
  for (int i = 0; i < 32; i += 8)
    t[ty + i][tx] = in[(size_t)(r0 + ty + i) * 1024 + c0 + tx];
  __syncthreads();
#pragma unroll
  for (int i = 0; i < 32; i += 8) {
    float v = t[tx][ty + i];
    if (mode == 1) v *= s1[c0 + ty + i];
    out[(size_t)(c0 + ty + i) * R + r0 + tx] = (_Float16)v;
  }
}

// ---------------------------------------------------------------------------
// 32x64 tile, NT, 4 waves (wc=N-half, wk=K-half), wave tile 32x32.
// LDS 48 KB: A 4x4KB + B 4x8KB. 3 gloads/wave/step, ahead 2, vmcnt(6/3/0),
// 1 barrier/K-step, XOR-swizzled staging. [R7/R10-proven]
// ---------------------------------------------------------------------------
template <int EPI>
__device__ __forceinline__ void gt32(
    const _Float16* __restrict__ A, int lda, const _Float16* __restrict__ B,
    int ldb, int nK, int N, int brow, int bcol, float* __restrict__ fA,
    float* __restrict__ fB, _Float16* __restrict__ oh,
    _Float16* __restrict__ oh2, const float* __restrict__ fC,
    float* __restrict__ ofin, _Float16* sm, int tid) {
  const int lane = tid & 63;
  const int w = tid >> 6;
  const int wc = w & 1;   // N half (32 cols)
  const int wk = w >> 1;  // K half within 64-step
  const int srow = lane >> 3;
  const int scol = ((lane & 7) ^ srow) << 3;
  const int a15 = lane & 15, hi = lane >> 4, l7 = lane & 7;

  const _Float16* apg = A + (size_t)(brow + (w << 3) + srow) * lda + scol;
  const _Float16* bpg = B + (size_t)(bcol + (w << 4) + srow) * ldb + scol;
  _Float16* AB = sm;          // 4 bufs x 2048 halfs
  _Float16* BB = sm + 8192;   // 4 bufs x 4096 halfs
  const int ca = ((wk << 2) + hi) ^ l7;
  int raddr[2], baddr[2];
#pragma unroll
  for (int mi = 0; mi < 2; ++mi)
    raddr[mi] = ((mi << 4) + a15) * 64 + (ca << 3);
#pragma unroll
  for (int ni = 0; ni < 2; ++ni)
    baddr[ni] = ((wc << 5) + (ni << 4) + a15) * 64 + (ca << 3);

  f32x4 acc[2][2] = {};
  __syncthreads();  // LDS handoff

#pragma unroll
  for (int p = 0; p < 2; ++p) {
    gload16(apg + p * 64, AB + p * 2048 + (w << 9));
    gload16(bpg + p * 64, BB + p * 4096 + (w << 10));
    gload16(bpg + p * 64 + (size_t)8 * ldb, BB + p * 4096 + (w << 10) + 512);
  }
  for (int kt = 0; kt < nK; ++kt) {
    if (kt + 2 < nK) {
      const int bf = (kt + 2) & 3;
      const int co = (kt + 2) << 6;
      gload16(apg + co, AB + bf * 2048 + (w << 9));
      gload16(bpg + co, BB + bf * 4096 + (w << 10));
      gload16(bpg + co + (size_t)8 * ldb, BB + bf * 4096 + (w << 10) + 512);
    }
    const int rem = nK - 1 - kt;
    if (rem >= 2)
      asm volatile("s_waitcnt vmcnt(6)" ::: "memory");
    else if (rem == 1)
      asm volatile("s_waitcnt vmcnt(3)" ::: "memory");
    else
      asm volatile("s_waitcnt vmcnt(0)" ::: "memory");
    __builtin_amdgcn_s_barrier();
    __builtin_amdgcn_sched_barrier(0);
    const _Float16* Ab = AB + (kt & 3) * 2048;
    const _Float16* Bb = BB + (kt & 3) * 4096;
    f16x8 av[2], bv[2];
    av[0] = *(const f16x8*)(Ab + raddr[0]);
    av[1] = *(const f16x8*)(Ab + raddr[1]);
    bv[0] = *(const f16x8*)(Bb + baddr[0]);
    bv[1] = *(const f16x8*)(Bb + baddr[1]);
#pragma unroll
    for (int mi = 0; mi < 2; ++mi)
#pragma unroll
      for (int ni = 0; ni < 2; ++ni)
        acc[mi][ni] = __builtin_amdgcn_mfma_f32_16x16x32_f16(
            av[mi], bv[ni], acc[mi][ni], 0, 0, 0);
  }
  __syncthreads();
  float* scr = (float*)sm;
  const int sl = (wc << 6) + lane;
  if (wk == 1) {
#pragma unroll
    for (int mi = 0; mi < 2; ++mi)
#pragma unroll
      for (int ni = 0; ni < 2; ++ni)
#pragma unroll
        for (int r = 0; r < 4; ++r)
          scr[(((mi << 1) + ni) * 4 + r) * 128 + sl] = acc[mi][ni][r];
  }
  __syncthreads();
  if (wk == 0) {
#pragma unroll
    for (int mi = 0; mi < 2; ++mi) {
#pragma unroll
      for (int ni = 0; ni < 2; ++ni) {
#pragma unroll
        for (int r = 0; r < 4; ++r) {
          const float v =
              acc[mi][ni][r] + scr[(((mi << 1) + ni) * 4 + r) * 128 + sl];
          const int row = brow + (mi << 4) + (hi << 2) + r;
          const int col = bcol + (wc << 5) + (ni << 4) + a15;
          const size_t idx = (size_t)row * N + col;
          if constexpr (EPI == EPI_SPLIT) {
            if (col < 1024)
              oh[(size_t)row * 1024 + col] = (_Float16)v;
            else
              oh2[(size_t)row * 1024 + (col - 1024)] = (_Float16)v;
          } else if constexpr (EPI == EPI_BH) {
            oh[idx] = (_Float16)v;
          } else if constexpr (EPI == EPI_YP) {
            ofin[idx] = v;  // ypart = betas2 @ V1^T (f32)
          } else if constexpr (EPI == EPI_SOFT) {
            fA[idx] = v;  // z0 f32
            float s = softt(v);
            fB[idx] = s;  // z1 f32
            oh[idx] = (_Float16)s;
          } else if constexpr (EPI == EPI_ZUP) {
            // z_new = soft(z0 + z - c@Ve^T)
            float t = fA[idx] + fB[idx] - v;
            float s = softt(t);
            fB[idx] = s;
            oh[idx] = (_Float16)s;
          } else {  // EPI_ZUPF: out = ypart + soft(z0 + z - v)
            float t = fA[idx] + fB[idx] - v;
            ofin[idx] = fC[idx] + softt(t);
          }
        }
      }
    }
  }
}

// ---------------------------------------------------------------------------
struct WS {
  const _Float16 *ve, *veT, *vt1, *Bcat, *x, *k0r, *vt0T, *q_r, *be2_r,
      *bet_r, *yb_r;
  _Float16 *q_w, *be2_w, *bet_w, *yb_w, *c_w, *zhA, *zhB;
  const _Float16* c_r;
  float *z0, *zf, *yp;
};

// XCD-chunked maps: 512 blocks (16 brow x 32 bcol), 256 blocks (16 x 16)
__device__ __forceinline__ void map512(int b, int& br, int& bc) {
  const int x = b & 7, i = b >> 3;
  bc = (x << 2) | (i & 3);
  br = i >> 2;
}
__device__ __forceinline__ void map256(int b, int& br, int& bc) {
  const int x = b & 7, i = b >> 3;
  bc = (x << 1) | (i & 1);
  br = i >> 1;
}

// D2: C1 [q|betas2] = x @ [Ke^T ; K1^T s1]  (512x2048, K=2048)
__global__ __launch_bounds__(256, 2) void kC1(WS p) {
  __shared__ __align__(16) _Float16 sm[24576];
  int br, bc;
  map512(blockIdx.x, br, bc);
  gt32<EPI_SPLIT>(p.x, 2048, p.Bcat, 2048, 32, 2048, br << 5, bc << 6,
                  nullptr, nullptr, p.q_w, p.be2_w, nullptr, nullptr, sm,
                  threadIdx.x);
}

// D3: [0,256) betas = q @ (s0 K0) (512x1024,K=1024); [256,768) ypart
__global__ __launch_bounds__(256, 2) void kBYP(WS p) {
  __shared__ __align__(16) _Float16 sm[24576];
  const int bid = blockIdx.x;
  int br, bc;
  if (bid < 256) {
    map256(bid, br, bc);
    gt32<EPI_BH>(p.q_r, 1024, p.k0r, 1024, 16, 1024, br << 5, bc << 6,
                 nullptr, nullptr, p.bet_w, nullptr, nullptr, nullptr, sm,
                 threadIdx.x);
  } else {
    map512(bid - 256, br, bc);
    gt32<EPI_YP>(p.be2_r, 1024, p.vt1, 1024, 16, 2048, br << 5, bc << 6,
                 nullptr, nullptr, nullptr, nullptr, nullptr, p.yp, sm,
                 threadIdx.x);
  }
}

// D4: yb = betas @ V0 (512x1024, K=1024)
__global__ __launch_bounds__(256, 2) void kYB(WS p) {
  __shared__ __align__(16) _Float16 sm[24576];
  int br, bc;
  map256(blockIdx.x, br, bc);
  gt32<EPI_BH>(p.bet_r, 1024, p.vt0T, 1024, 16, 1024, br << 5, bc << 6,
               nullptr, nullptr, p.yb_w, nullptr, nullptr, nullptr, sm,
               threadIdx.x);
}

// D5: z0 = yb @ Ve^T (512x2048, K=1024), soft fused -> z0_f, z_f, zhA
__global__ __launch_bounds__(256, 2) void kZ0(WS p) {
  __shared__ __align__(16) _Float16 sm[24576];
  int br, bc;
  map512(blockIdx.x, br, bc);
  gt32<EPI_SOFT>(p.yb_r, 1024, p.ve, 1024, 16, 2048, br << 5, bc << 6, p.z0,
                 p.zf, p.zhA, nullptr, nullptr, nullptr, sm, threadIdx.x);
}

// c = z @ Ve (512x1024, K=2048)
template <bool AB>
__global__ __launch_bounds__(256, 2) void kC(WS p) {
  __shared__ __align__(16) _Float16 sm[24576];
  int br, bc;
  map256(blockIdx.x, br, bc);
  gt32<EPI_BH>(AB ? p.zhA : p.zhB, 2048, p.veT, 2048, 32, 1024, br << 5,
               bc << 6, nullptr, nullptr, p.c_w, nullptr, nullptr, nullptr,
               sm, threadIdx.x);
}

// z = soft(z0 + z - c@Ve^T) (512x2048, K=1024)
template <bool AB>
__global__ __launch_bounds__(256, 2) void kZU(WS p) {
  __shared__ __align__(16) _Float16 sm[24576];
  int br, bc;
  map512(blockIdx.x, br, bc);
  gt32<EPI_ZUP>(p.c_r, 1024, p.ve, 1024, 16, 2048, br << 5, bc << 6, p.z0,
                p.zf, AB ? p.zhB : p.zhA, nullptr, nullptr, nullptr, sm,
                threadIdx.x);
}

// D13: out = ypart + soft(z0 + z - c@Ve^T)
__global__ __launch_bounds__(256, 2) void kZUF(WS p, float* out) {
  __shared__ __align__(16) _Float16 sm[24576];
  int br, bc;
  map512(blockIdx.x, br, bc);
  gt32<EPI_ZUPF>(p.c_r, 1024, p.ve, 1024, 16, 2048, br << 5, bc << 6, p.z0,
                 p.zf, nullptr, nullptr, p.yp, out, sm, threadIdx.x);
}

// ---------------------------------------------------------------------------
extern "C" void kernel_launch(void* const* d_in, const int* in_sizes, int n_in,
                              void* d_out, int out_size, void* d_ws,
                              size_t ws_size, hipStream_t stream) {
  const float* x = (const float*)d_in[0];          // (512,2048)
  const float* key_enc = (const float*)d_in[1];    // (2048,1024)
  const float* val_enc = (const float*)d_in[2];    // (2048,1024)
  const float* keys_t0 = (const float*)d_in[3];    // (1024,1024)
  const float* vals_t0 = (const float*)d_in[4];    // (1024,1024)
  const float* scales_t0 = (const float*)d_in[5];  // (1024,)
  const float* keys_t1 = (const float*)d_in[6];    // (2048,1024)
  const float* vals_t1 = (const float*)d_in[7];    // (2048,1024)
  const float* scales_t1 = (const float*)d_in[8];  // (1024,)

  // workspace (half offsets; 1M = 1048576), lifetime-overlaid, 38 MB
  constexpr size_t M1 = 1048576;
  _Float16* ws = (_Float16*)d_ws;
  _Float16* ve_h = ws;                    // [0,2M)   Ve natural (D5..D13 B)
  _Float16* veT = ws + 2 * M1;            // [2M,4M)  Ve^T (c-GEMM B)
  _Float16* vt1_h = ws + 4 * M1;          // [4M,6M)  vals_t1 (D3 ypart B)
  _Float16* Bcat = ws + 6 * M1;           // [6M,10M) [Ke^T;K1^T s1]; dead @D3
  _Float16* zhA = ws + 6 * M1;            //   overlay (D5+): z f16 A
  float* z0_f = (float*)(ws + 7 * M1);    //   overlay (D5+): z0 f32 (4MB)
  _Float16* zhB = ws + 9 * M1;            //   overlay (D7+): z f16 B
  _Float16* x_h = ws + 10 * M1;           // [10M,11M) x f16 (D2 A)
  _Float16* k0r = ws + 11 * M1;           // [11M,12M) s0-row-scaled K0; dead @D4
  _Float16* c_h = ws + 11 * M1;           //   overlay (D6+): c f16 (0.5M)
  _Float16* vt0T = ws + 12 * M1;          // [12M,13M) V0^T (D4 B)
  _Float16* q_h = ws + 13 * M1;           // [13M,13.5M) q (D2 out)
  _Float16* be2 = ws + 13 * M1 + 524288;  // [13.5M,14M) betas2 (D2 out)
  _Float16* bet_h = ws + 14 * M1;         // [14M,14.5M) betas (D3 out)
  _Float16* yb_h = ws + 14 * M1 + 524288; // [14.5M,15M) yb (D4 out)
  float* z_f = (float*)(ws + 15 * M1);    // [15M,17M) z f32 (4MB)
  float* yp = (float*)(ws + 17 * M1);     // [17M,19M) ypart f32 (4MB)

  WS p;
  p.ve = ve_h; p.veT = veT; p.vt1 = vt1_h; p.Bcat = Bcat; p.x = x_h;
  p.k0r = k0r; p.vt0T = vt0T; p.q_r = q_h; p.q_w = q_h;
  p.be2_r = be2; p.be2_w = be2; p.bet_r = bet_h; p.bet_w = bet_h;
  p.yb_r = yb_h; p.yb_w = yb_h; p.c_r = c_h; p.c_w = c_h;
  p.zhA = zhA; p.zhB = zhB; p.z0 = z0_f; p.zf = z_f; p.yp = yp;

  // D1: conversions
  convAll<<<dim3(32, 64, 5), dim3(32, 8), 0, stream>>>(
      key_enc, keys_t1, vals_t0, val_enc, Bcat, Bcat + 2 * M1, vt0T, veT,
      scales_t1, scales_t0, (const float4*)x, (f16x4*)x_h,
      (const float4*)val_enc, (f16x4*)ve_h, (const float4*)vals_t1,
      (f16x4*)vt1_h, (const float4*)keys_t0, (f16x4*)k0r);
  // D2: C1 [q | betas2]
  kC1<<<512, 256, 0, stream>>>(p);
  // D3: betas || ypart
  kBYP<<<768, 256, 0, stream>>>(p);
  // D4: yb = betas @ V0
  kYB<<<256, 256, 0, stream>>>(p);
  // D5: z0 = yb @ Ve^T (soft) -> z1
  kZ0<<<512, 256, 0, stream>>>(p);
  // D6..D12: ISTA iters 2..5 (c then zup; zh ping-pong)
  kC<true><<<256, 256, 0, stream>>>(p);    // c(z1) from zhA
  kZU<true><<<512, 256, 0, stream>>>(p);   // z2 -> zhB
  kC<false><<<256, 256, 0, stream>>>(p);   // c(z2) from zhB
  kZU<false><<<512, 256, 0, stream>>>(p);  // z3 -> zhA
  kC<true><<<256, 256, 0, stream>>>(p);    // c(z3) from zhA
  kZU<true><<<512, 256, 0, stream>>>(p);   // z4 -> zhB
  kC<false><<<256, 256, 0, stream>>>(p);   // c(z4) from zhB
  // D13: final zup + out = ypart + soft(...)
  kZUF<<<512, 256, 0, stream>>>(p, (float*)d_out);
}